// Round 9
// baseline (211.983 us; speedup 1.0000x reference)
//
#include <hip/hip_runtime.h>
#include <hip/hip_bf16.h>
#include <stdint.h>

#define N_TOK 8192
#define DDIM 1024
#define FDIM 4096
#define NEXP 8

typedef __attribute__((ext_vector_type(8))) short short8;
typedef __attribute__((ext_vector_type(4))) float f32x4;

__device__ __forceinline__ ushort f2bf(float f) {
  uint32_t u = __float_as_uint(f);
  u += 0x7FFF + ((u >> 16) & 1);   // RNE
  return (ushort)(u >> 16);
}

__device__ __forceinline__ void gload16(const void* g, void* l) {
  __builtin_amdgcn_global_load_lds((const __attribute__((address_space(1))) void*)g,
                                   (__attribute__((address_space(3))) void*)l, 16, 0, 0);
}

// ---------- merged prep: weight casts (blocks 0..8191) + router (blocks 8192..10239) ----------
__global__ __launch_bounds__(256) void prep_kernel(
    const float* __restrict__ wi, const float* __restrict__ wo,
    ushort* __restrict__ wib, ushort* __restrict__ wob,
    const float* __restrict__ x, const float* __restrict__ gW, const float* __restrict__ gb,
    const float* __restrict__ lA, int* __restrict__ top1, float* __restrict__ coeff,
    ushort* __restrict__ xb) {
  if (blockIdx.x < 8192) {
    // cast both weight matrices
    const int N1 = FDIM * DDIM / 4;
    int i = blockIdx.x * 256 + threadIdx.x;
    const float* src;
    ushort* dst;
    int j;
    if (i < N1) { src = wi; dst = wib; j = i; }
    else        { src = wo; dst = wob; j = i - N1; }
    float4 v = reinterpret_cast<const float4*>(src)[j];
    ushort4 o;
    o.x = f2bf(v.x); o.y = f2bf(v.y); o.z = f2bf(v.z); o.w = f2bf(v.w);
    reinterpret_cast<ushort4*>(dst)[j] = o;
    return;
  }
  // ---- router (proven) ----
  const int lane = threadIdx.x & 63;
  const int wid = threadIdx.x >> 6;
  const int tok = (blockIdx.x - 8192) * 4 + wid;
  const float* xp = x + (size_t)tok * DDIM;
  float4 xv[4];
#pragma unroll
  for (int i = 0; i < 4; ++i)
    xv[i] = *reinterpret_cast<const float4*>(xp + i * 256 + lane * 4);
#pragma unroll
  for (int i = 0; i < 4; ++i) {
    ushort4 o;
    o.x = f2bf(xv[i].x); o.y = f2bf(xv[i].y); o.z = f2bf(xv[i].z); o.w = f2bf(xv[i].w);
    *reinterpret_cast<ushort4*>(xb + (size_t)tok * DDIM + i * 256 + lane * 4) = o;
  }
  double lg[NEXP];
#pragma unroll
  for (int e = 0; e < NEXP; ++e) {
    const float* gp = gW + e * DDIM;
    double s = 0.0;
#pragma unroll
    for (int i = 0; i < 4; ++i) {
      float4 g = *reinterpret_cast<const float4*>(gp + i * 256 + lane * 4);
      s += (double)xv[i].x * g.x + (double)xv[i].y * g.y +
           (double)xv[i].z * g.z + (double)xv[i].w * g.w;
    }
    lg[e] = s;
  }
#pragma unroll
  for (int e = 0; e < NEXP; ++e)
    for (int off = 32; off > 0; off >>= 1) lg[e] += __shfl_xor(lg[e], off);
  int best = 0;
  double bv = lg[0] + (double)gb[0];
#pragma unroll
  for (int e = 1; e < NEXP; ++e) {
    double v = lg[e] + (double)gb[e];
    if (v > bv) { bv = v; best = e; }
  }
  float c[4];
#pragma unroll
  for (int r = 0; r < 4; ++r) {
    const float* ap = lA + ((size_t)best * 4 + r) * DDIM;
    float s = 0.f;
#pragma unroll
    for (int i = 0; i < 4; ++i) {
      float4 a = *reinterpret_cast<const float4*>(ap + i * 256 + lane * 4);
      s = fmaf(xv[i].x, a.x, s); s = fmaf(xv[i].y, a.y, s);
      s = fmaf(xv[i].z, a.z, s); s = fmaf(xv[i].w, a.w, s);
    }
    for (int off = 32; off > 0; off >>= 1) s += __shfl_xor(s, off);
    c[r] = s;
  }
  if (lane == 0) {
    top1[tok] = best;
    float4 cc; cc.x = c[0]; cc.y = c[1]; cc.z = c[2]; cc.w = c[3];
    *reinterpret_cast<float4*>(coeff + tok * 4) = cc;
  }
}

// =====================================================================
// GEMM1: inter = relu(xb[8192,1024] @ wiWb[4096,1024]^T + wi_b + lora)
// Structure = gemm2's measured-good m97 128x128 (row-major LDS, BK=32,
// 256 thr, compiler-scheduled __syncthreads, natural dim3(64,32) grid
// -> XCD=brow%8, per-XCD footprint 10.5MB) + R2-proven LDS-staged lora
// epilogue (coalesced, overlaid on staging LDS after the K loop).
// =====================================================================
__global__ __launch_bounds__(256) void gemm1_kernel(
    const ushort* __restrict__ A, const ushort* __restrict__ B,
    const float* __restrict__ bias, const int* __restrict__ top1,
    const float4* __restrict__ coeff, const float4* __restrict__ loraB,
    ushort* __restrict__ C) {
  __shared__ __align__(16) ushort lds[9472];   // 18.94 KB: 16KB staging / 18.5KB overlay
  const int tid = threadIdx.x;
  const int lane = tid & 63;
  const int wid = tid >> 6;
  const int wr = wid >> 1, wc = wid & 1;       // 2x2 waves, each 64x64
  const int brow = blockIdx.x, bcol = blockIdx.y;

  f32x4 acc[4][4] = {};

  const int srow = tid >> 2;
  const int scol = (tid & 3) * 8;
  const ushort* gA0 = A + (size_t)(brow * 128 + srow) * DDIM + scol;
  const ushort* gA1 = A + (size_t)(brow * 128 + 64 + srow) * DDIM + scol;
  const ushort* gB0 = B + (size_t)(bcol * 128 + srow) * DDIM + scol;
  const ushort* gB1 = B + (size_t)(bcol * 128 + 64 + srow) * DDIM + scol;
  ushort* lA0 = lds + tid * 8;                 // lA = lds[0..4095], row-major [128][32]
  ushort* lA1 = lds + 2048 + tid * 8;
  ushort* lB0 = lds + 4096 + tid * 8;          // lB = lds[4096..8191]
  ushort* lB1 = lds + 4096 + 2048 + tid * 8;

  const int offA = (wr * 64 + (lane & 15)) * 32 + (lane >> 4) * 8;
  const int offB = 4096 + (wc * 64 + (lane & 15)) * 32 + (lane >> 4) * 8;

  for (int k0 = 0; k0 < DDIM; k0 += 32) {
    gload16(gA0 + k0, lA0);
    gload16(gA1 + k0, lA1);
    gload16(gB0 + k0, lB0);
    gload16(gB1 + k0, lB1);
    __syncthreads();
    short8 af[4], bf[4];
#pragma unroll
    for (int m = 0; m < 4; ++m)
      af[m] = *reinterpret_cast<const short8*>(lds + offA + m * 16 * 32);
#pragma unroll
    for (int n = 0; n < 4; ++n)
      bf[n] = *reinterpret_cast<const short8*>(lds + offB + n * 16 * 32);
#pragma unroll
    for (int n = 0; n < 4; ++n)
#pragma unroll
      for (int m = 0; m < 4; ++m)
        acc[m][n] = __builtin_amdgcn_mfma_f32_16x16x32_bf16(af[m], bf[n], acc[m][n], 0, 0, 0);
    __syncthreads();
  }

  // ---- epilogue: LDS-staged lora/coeff/top1 (proven), fused bias+lora+relu ----
  float4* lora_s  = (float4*)lds;                    // [8][128] = 16 KB
  float4* coeff_s = (float4*)((char*)lds + 16384);   // [128]    =  2 KB
  int*    top1_s  = (int*)  ((char*)lds + 18432);    // [128]    = 512 B
#pragma unroll
  for (int i = 0; i < 4; ++i) {
    int idx = tid + i * 256;                         // 1024 = 8 experts x 128 cols
    lora_s[idx] = loraB[(size_t)(idx >> 7) * FDIM + bcol * 128 + (idx & 127)];
  }
  if (tid < 128) {
    coeff_s[tid] = coeff[brow * 128 + tid];
    top1_s[tid]  = top1[brow * 128 + tid];
  }
  __syncthreads();

  const int ccb = wc * 64 + (lane & 15);
  float bias4[4];
#pragma unroll
  for (int fn = 0; fn < 4; ++fn) bias4[fn] = bias[bcol * 128 + ccb + fn * 16];
#pragma unroll
  for (int fm = 0; fm < 4; ++fm) {
#pragma unroll
    for (int q = 0; q < 4; ++q) {
      const int tl = wr * 64 + fm * 16 + ((lane >> 4) << 2) + q;
      const int e = top1_s[tl];
      const float4 cf = coeff_s[tl];
      ushort* crow = C + (size_t)(brow * 128 + tl) * FDIM + bcol * 128;
#pragma unroll
      for (int fn = 0; fn < 4; ++fn) {
        const int cc = ccb + fn * 16;
        const float4 l4 = lora_s[e * 128 + cc];
        float v = acc[fm][fn][q] + bias4[fn] +
                  cf.x * l4.x + cf.y * l4.y + cf.z * l4.z + cf.w * l4.w;
        crow[cc] = f2bf(fmaxf(v, 0.f));
      }
    }
  }
}

// =====================================================================
// GEMM2: EXACT round-1/8 kernel (measured ~77us, ~893 TF).
// =====================================================================
__global__ __launch_bounds__(256) void gemm2_kernel(
    const ushort* __restrict__ A, const ushort* __restrict__ B,
    const float* __restrict__ bias, float* __restrict__ C) {
  __shared__ __align__(16) ushort lA[128 * 32];
  __shared__ __align__(16) ushort lB[128 * 32];
  const int tid = threadIdx.x;
  const int lane = tid & 63;
  const int wid = tid >> 6;
  const int wr = wid >> 1, wc = wid & 1;
  const int brow = blockIdx.x, bcol = blockIdx.y;

  f32x4 acc[4][4] = {};

  const int srow = tid >> 2;
  const int scol = (tid & 3) * 8;
  const ushort* gA0 = A + (size_t)(brow * 128 + srow) * FDIM + scol;
  const ushort* gA1 = A + (size_t)(brow * 128 + 64 + srow) * FDIM + scol;
  const ushort* gB0 = B + (size_t)(bcol * 128 + srow) * FDIM + scol;
  const ushort* gB1 = B + (size_t)(bcol * 128 + 64 + srow) * FDIM + scol;
  ushort* lA0 = lA + tid * 8;
  ushort* lA1 = lA + 2048 + tid * 8;
  ushort* lB0 = lB + tid * 8;
  ushort* lB1 = lB + 2048 + tid * 8;

  const int offA = (wr * 64 + (lane & 15)) * 32 + (lane >> 4) * 8;
  const int offB = (wc * 64 + (lane & 15)) * 32 + (lane >> 4) * 8;

  for (int k0 = 0; k0 < FDIM; k0 += 32) {
    gload16(gA0 + k0, lA0);
    gload16(gA1 + k0, lA1);
    gload16(gB0 + k0, lB0);
    gload16(gB1 + k0, lB1);
    __syncthreads();
    short8 af[4], bf[4];
#pragma unroll
    for (int m = 0; m < 4; ++m)
      af[m] = *reinterpret_cast<const short8*>(lA + offA + m * 16 * 32);
#pragma unroll
    for (int n = 0; n < 4; ++n)
      bf[n] = *reinterpret_cast<const short8*>(lB + offB + n * 16 * 32);
#pragma unroll
    for (int n = 0; n < 4; ++n)
#pragma unroll
      for (int m = 0; m < 4; ++m)
        acc[m][n] = __builtin_amdgcn_mfma_f32_16x16x32_bf16(af[m], bf[n], acc[m][n], 0, 0, 0);
    __syncthreads();
  }

  const int dbase = bcol * 128 + wc * 64 + (lane & 15);
  const int tokbase = brow * 128 + wr * 64 + ((lane >> 4) << 2);
  float bias4[4];
#pragma unroll
  for (int n = 0; n < 4; ++n) bias4[n] = bias[dbase + n * 16];
#pragma unroll
  for (int m = 0; m < 4; ++m) {
#pragma unroll
    for (int q = 0; q < 4; ++q) {
      const int tok = tokbase + m * 16 + q;
#pragma unroll
      for (int n = 0; n < 4; ++n)
        C[(size_t)tok * DDIM + dbase + n * 16] = acc[m][n][q] + bias4[n];
    }
  }
}

extern "C" void kernel_launch(void* const* d_in, const int* in_sizes, int n_in,
                              void* d_out, int out_size, void* d_ws, size_t ws_size,
                              hipStream_t stream) {
  const float* x      = (const float*)d_in[0];
  const float* gate_W = (const float*)d_in[1];
  const float* gate_b = (const float*)d_in[2];
  const float* wi_W   = (const float*)d_in[3];
  const float* wi_b   = (const float*)d_in[4];
  const float* wo_W   = (const float*)d_in[5];
  const float* wo_b   = (const float*)d_in[6];
  const float* lora_A = (const float*)d_in[7];
  const float* lora_B = (const float*)d_in[8];
  float* out = (float*)d_out;

  char* ws = (char*)d_ws;
  ushort* xb    = (ushort*)(ws);                       // 16.78 MB
  ushort* wiWb  = (ushort*)(ws + 16777216);            //  8.39 MB
  ushort* woWb  = (ushort*)(ws + 25165824);            //  8.39 MB
  ushort* inter = (ushort*)(ws + 33554432);            // 67.1  MB
  int*    top1  = (int*)   (ws + 100663296);           // 32 KB
  float*  coeff = (float*) (ws + 100696064);           // 128 KB

  prep_kernel<<<10240, 256, 0, stream>>>(wi_W, wo_W, wiWb, woWb,
                                         x, gate_W, gate_b, lora_A, top1, coeff, xb);
  gemm1_kernel<<<dim3(N_TOK / 128, FDIM / 128), 256, 0, stream>>>(
      xb, wiWb, wi_b, top1, (const float4*)coeff, (const float4*)lora_B, inter);
  gemm2_kernel<<<dim3(N_TOK / 128, DDIM / 128), 256, 0, stream>>>(inter, woWb, wo_b, out);
}

// Round 10
// 193.397 us; speedup vs baseline: 1.0961x; 1.0961x over previous
//
#include <hip/hip_runtime.h>
#include <hip/hip_bf16.h>
#include <stdint.h>

#define N_TOK 8192
#define DDIM 1024
#define FDIM 4096
#define NEXP 8

typedef __attribute__((ext_vector_type(8))) short short8;
typedef __attribute__((ext_vector_type(4))) float f32x4;

__device__ __forceinline__ ushort f2bf(float f) {
  uint32_t u = __float_as_uint(f);
  u += 0x7FFF + ((u >> 16) & 1);   // RNE
  return (ushort)(u >> 16);
}

__device__ __forceinline__ void gload16(const void* g, void* l) {
  __builtin_amdgcn_global_load_lds((const __attribute__((address_space(1))) void*)g,
                                   (__attribute__((address_space(3))) void*)l, 16, 0, 0);
}

// ---------- merged prep: weight casts (blocks 0..8191) + router (blocks 8192..10239) ----------
__global__ __launch_bounds__(256) void prep_kernel(
    const float* __restrict__ wi, const float* __restrict__ wo,
    ushort* __restrict__ wib, ushort* __restrict__ wob,
    const float* __restrict__ x, const float* __restrict__ gW, const float* __restrict__ gb,
    const float* __restrict__ lA, int* __restrict__ top1, float* __restrict__ coeff,
    ushort* __restrict__ xb) {
  if (blockIdx.x < 8192) {
    const int N1 = FDIM * DDIM / 4;
    int i = blockIdx.x * 256 + threadIdx.x;
    const float* src;
    ushort* dst;
    int j;
    if (i < N1) { src = wi; dst = wib; j = i; }
    else        { src = wo; dst = wob; j = i - N1; }
    float4 v = reinterpret_cast<const float4*>(src)[j];
    ushort4 o;
    o.x = f2bf(v.x); o.y = f2bf(v.y); o.z = f2bf(v.z); o.w = f2bf(v.w);
    reinterpret_cast<ushort4*>(dst)[j] = o;
    return;
  }
  // ---- router (proven) ----
  const int lane = threadIdx.x & 63;
  const int wid = threadIdx.x >> 6;
  const int tok = (blockIdx.x - 8192) * 4 + wid;
  const float* xp = x + (size_t)tok * DDIM;
  float4 xv[4];
#pragma unroll
  for (int i = 0; i < 4; ++i)
    xv[i] = *reinterpret_cast<const float4*>(xp + i * 256 + lane * 4);
#pragma unroll
  for (int i = 0; i < 4; ++i) {
    ushort4 o;
    o.x = f2bf(xv[i].x); o.y = f2bf(xv[i].y); o.z = f2bf(xv[i].z); o.w = f2bf(xv[i].w);
    *reinterpret_cast<ushort4*>(xb + (size_t)tok * DDIM + i * 256 + lane * 4) = o;
  }
  double lg[NEXP];
#pragma unroll
  for (int e = 0; e < NEXP; ++e) {
    const float* gp = gW + e * DDIM;
    double s = 0.0;
#pragma unroll
    for (int i = 0; i < 4; ++i) {
      float4 g = *reinterpret_cast<const float4*>(gp + i * 256 + lane * 4);
      s += (double)xv[i].x * g.x + (double)xv[i].y * g.y +
           (double)xv[i].z * g.z + (double)xv[i].w * g.w;
    }
    lg[e] = s;
  }
#pragma unroll
  for (int e = 0; e < NEXP; ++e)
    for (int off = 32; off > 0; off >>= 1) lg[e] += __shfl_xor(lg[e], off);
  int best = 0;
  double bv = lg[0] + (double)gb[0];
#pragma unroll
  for (int e = 1; e < NEXP; ++e) {
    double v = lg[e] + (double)gb[e];
    if (v > bv) { bv = v; best = e; }
  }
  float c[4];
#pragma unroll
  for (int r = 0; r < 4; ++r) {
    const float* ap = lA + ((size_t)best * 4 + r) * DDIM;
    float s = 0.f;
#pragma unroll
    for (int i = 0; i < 4; ++i) {
      float4 a = *reinterpret_cast<const float4*>(ap + i * 256 + lane * 4);
      s = fmaf(xv[i].x, a.x, s); s = fmaf(xv[i].y, a.y, s);
      s = fmaf(xv[i].z, a.z, s); s = fmaf(xv[i].w, a.w, s);
    }
    for (int off = 32; off > 0; off >>= 1) s += __shfl_xor(s, off);
    c[r] = s;
  }
  if (lane == 0) {
    top1[tok] = best;
    float4 cc; cc.x = c[0]; cc.y = c[1]; cc.z = c[2]; cc.w = c[3];
    *reinterpret_cast<float4*>(coeff + tok * 4) = cc;
  }
}

// =====================================================================
// GEMM1: inter = relu(xb[8192,1024] @ wiWb[4096,1024]^T + wi_b + lora)
// m97 128x128 row-major LDS + BK=64 unroll-by-2 (dual 32-k sub-buffers,
// one barrier pair per 64-K -> half the drain stalls). 16 k-iters.
// LDS 32KB: A0[0,8K) A1[8K,16K) B0[16K,24K) B1[24K,32K) bytes.
// Epilogue overlay (18.5KB) reuses the same LDS after the K loop.
// =====================================================================
__global__ __launch_bounds__(256) void gemm1_kernel(
    const ushort* __restrict__ A, const ushort* __restrict__ B,
    const float* __restrict__ bias, const int* __restrict__ top1,
    const float4* __restrict__ coeff, const float4* __restrict__ loraB,
    ushort* __restrict__ C) {
  __shared__ __align__(16) ushort lds[16384];   // 32 KB
  const int tid = threadIdx.x;
  const int lane = tid & 63;
  const int wid = tid >> 6;
  const int wr = wid >> 1, wc = wid & 1;        // 2x2 waves, each 64x64
  const int brow = blockIdx.x, bcol = blockIdx.y;

  f32x4 acc[4][4] = {};

  const int srow = tid >> 2;                    // 0..63
  const int scol = (tid & 3) * 8;               // 0,8,16,24
  const ushort* gA0 = A + (size_t)(brow * 128 + srow) * DDIM + scol;
  const ushort* gA1 = A + (size_t)(brow * 128 + 64 + srow) * DDIM + scol;
  const ushort* gB0 = B + (size_t)(bcol * 128 + srow) * DDIM + scol;
  const ushort* gB1 = B + (size_t)(bcol * 128 + 64 + srow) * DDIM + scol;
  ushort* const d0 = lds + tid * 8;             // row-major [128][32] per region

  const int offA = (wr * 64 + (lane & 15)) * 32 + (lane >> 4) * 8;
  const int offB = 8192 + (wc * 64 + (lane & 15)) * 32 + (lane >> 4) * 8;

  for (int k0 = 0; k0 < DDIM; k0 += 64) {
    // k-half 0 -> regions A0/B0
    gload16(gA0 + k0, d0);          gload16(gA1 + k0, d0 + 2048);
    gload16(gB0 + k0, d0 + 8192);   gload16(gB1 + k0, d0 + 8192 + 2048);
    // k-half 1 -> regions A1/B1
    gload16(gA0 + k0 + 32, d0 + 4096);          gload16(gA1 + k0 + 32, d0 + 4096 + 2048);
    gload16(gB0 + k0 + 32, d0 + 12288);         gload16(gB1 + k0 + 32, d0 + 12288 + 2048);
    __syncthreads();
    short8 af[4], bf[4];
#pragma unroll
    for (int m = 0; m < 4; ++m)
      af[m] = *reinterpret_cast<const short8*>(lds + offA + m * 512);
#pragma unroll
    for (int n = 0; n < 4; ++n)
      bf[n] = *reinterpret_cast<const short8*>(lds + offB + n * 512);
#pragma unroll
    for (int n = 0; n < 4; ++n)
#pragma unroll
      for (int m = 0; m < 4; ++m)
        acc[m][n] = __builtin_amdgcn_mfma_f32_16x16x32_bf16(af[m], bf[n], acc[m][n], 0, 0, 0);
#pragma unroll
    for (int m = 0; m < 4; ++m)
      af[m] = *reinterpret_cast<const short8*>(lds + 4096 + offA + m * 512);
#pragma unroll
    for (int n = 0; n < 4; ++n)
      bf[n] = *reinterpret_cast<const short8*>(lds + 4096 + offB + n * 512);
#pragma unroll
    for (int n = 0; n < 4; ++n)
#pragma unroll
      for (int m = 0; m < 4; ++m)
        acc[m][n] = __builtin_amdgcn_mfma_f32_16x16x32_bf16(af[m], bf[n], acc[m][n], 0, 0, 0);
    __syncthreads();
  }

  // ---- epilogue: LDS-staged lora/coeff/top1 (proven), fused bias+lora+relu ----
  float4* lora_s  = (float4*)lds;                    // [8][128] = 16 KB
  float4* coeff_s = (float4*)((char*)lds + 16384);   // [128]    =  2 KB
  int*    top1_s  = (int*)  ((char*)lds + 18432);    // [128]    = 512 B
#pragma unroll
  for (int i = 0; i < 4; ++i) {
    int idx = tid + i * 256;                         // 1024 = 8 experts x 128 cols
    lora_s[idx] = loraB[(size_t)(idx >> 7) * FDIM + bcol * 128 + (idx & 127)];
  }
  if (tid < 128) {
    coeff_s[tid] = coeff[brow * 128 + tid];
    top1_s[tid]  = top1[brow * 128 + tid];
  }
  __syncthreads();

  const int ccb = wc * 64 + (lane & 15);
  float bias4[4];
#pragma unroll
  for (int fn = 0; fn < 4; ++fn) bias4[fn] = bias[bcol * 128 + ccb + fn * 16];
#pragma unroll
  for (int fm = 0; fm < 4; ++fm) {
#pragma unroll
    for (int q = 0; q < 4; ++q) {
      const int tl = wr * 64 + fm * 16 + ((lane >> 4) << 2) + q;
      const int e = top1_s[tl];
      const float4 cf = coeff_s[tl];
      ushort* crow = C + (size_t)(brow * 128 + tl) * FDIM + bcol * 128;
#pragma unroll
      for (int fn = 0; fn < 4; ++fn) {
        const int cc = ccb + fn * 16;
        const float4 l4 = lora_s[e * 128 + cc];
        float v = acc[fm][fn][q] + bias4[fn] +
                  cf.x * l4.x + cf.y * l4.y + cf.z * l4.z + cf.w * l4.w;
        crow[cc] = f2bf(fmaxf(v, 0.f));
      }
    }
  }
}

// =====================================================================
// GEMM2: out = inter[8192,4096] @ woWb[1024,4096]^T + wo_b   (f32 out)
// Round-1 proven m97 128x128 + BK=64 unroll-by-2 (64 k-iters).
// =====================================================================
__global__ __launch_bounds__(256) void gemm2_kernel(
    const ushort* __restrict__ A, const ushort* __restrict__ B,
    const float* __restrict__ bias, float* __restrict__ C) {
  __shared__ __align__(16) ushort lds[16384];   // 32 KB
  const int tid = threadIdx.x;
  const int lane = tid & 63;
  const int wid = tid >> 6;
  const int wr = wid >> 1, wc = wid & 1;
  const int brow = blockIdx.x, bcol = blockIdx.y;

  f32x4 acc[4][4] = {};

  const int srow = tid >> 2;
  const int scol = (tid & 3) * 8;
  const ushort* gA0 = A + (size_t)(brow * 128 + srow) * FDIM + scol;
  const ushort* gA1 = A + (size_t)(brow * 128 + 64 + srow) * FDIM + scol;
  const ushort* gB0 = B + (size_t)(bcol * 128 + srow) * FDIM + scol;
  const ushort* gB1 = B + (size_t)(bcol * 128 + 64 + srow) * FDIM + scol;
  ushort* const d0 = lds + tid * 8;

  const int offA = (wr * 64 + (lane & 15)) * 32 + (lane >> 4) * 8;
  const int offB = 8192 + (wc * 64 + (lane & 15)) * 32 + (lane >> 4) * 8;

  for (int k0 = 0; k0 < FDIM; k0 += 64) {
    gload16(gA0 + k0, d0);          gload16(gA1 + k0, d0 + 2048);
    gload16(gB0 + k0, d0 + 8192);   gload16(gB1 + k0, d0 + 8192 + 2048);
    gload16(gA0 + k0 + 32, d0 + 4096);          gload16(gA1 + k0 + 32, d0 + 4096 + 2048);
    gload16(gB0 + k0 + 32, d0 + 12288);         gload16(gB1 + k0 + 32, d0 + 12288 + 2048);
    __syncthreads();
    short8 af[4], bf[4];
#pragma unroll
    for (int m = 0; m < 4; ++m)
      af[m] = *reinterpret_cast<const short8*>(lds + offA + m * 512);
#pragma unroll
    for (int n = 0; n < 4; ++n)
      bf[n] = *reinterpret_cast<const short8*>(lds + offB + n * 512);
#pragma unroll
    for (int n = 0; n < 4; ++n)
#pragma unroll
      for (int m = 0; m < 4; ++m)
        acc[m][n] = __builtin_amdgcn_mfma_f32_16x16x32_bf16(af[m], bf[n], acc[m][n], 0, 0, 0);
#pragma unroll
    for (int m = 0; m < 4; ++m)
      af[m] = *reinterpret_cast<const short8*>(lds + 4096 + offA + m * 512);
#pragma unroll
    for (int n = 0; n < 4; ++n)
      bf[n] = *reinterpret_cast<const short8*>(lds + 4096 + offB + n * 512);
#pragma unroll
    for (int n = 0; n < 4; ++n)
#pragma unroll
      for (int m = 0; m < 4; ++m)
        acc[m][n] = __builtin_amdgcn_mfma_f32_16x16x32_bf16(af[m], bf[n], acc[m][n], 0, 0, 0);
    __syncthreads();
  }

  const int dbase = bcol * 128 + wc * 64 + (lane & 15);
  const int tokbase = brow * 128 + wr * 64 + ((lane >> 4) << 2);
  float bias4[4];
#pragma unroll
  for (int n = 0; n < 4; ++n) bias4[n] = bias[dbase + n * 16];
#pragma unroll
  for (int m = 0; m < 4; ++m) {
#pragma unroll
    for (int q = 0; q < 4; ++q) {
      const int tok = tokbase + m * 16 + q;
#pragma unroll
      for (int n = 0; n < 4; ++n)
        C[(size_t)tok * DDIM + dbase + n * 16] = acc[m][n][q] + bias4[n];
    }
  }
}

extern "C" void kernel_launch(void* const* d_in, const int* in_sizes, int n_in,
                              void* d_out, int out_size, void* d_ws, size_t ws_size,
                              hipStream_t stream) {
  const float* x      = (const float*)d_in[0];
  const float* gate_W = (const float*)d_in[1];
  const float* gate_b = (const float*)d_in[2];
  const float* wi_W   = (const float*)d_in[3];
  const float* wi_b   = (const float*)d_in[4];
  const float* wo_W   = (const float*)d_in[5];
  const float* wo_b   = (const float*)d_in[6];
  const float* lora_A = (const float*)d_in[7];
  const float* lora_B = (const float*)d_in[8];
  float* out = (float*)d_out;

  char* ws = (char*)d_ws;
  ushort* xb    = (ushort*)(ws);                       // 16.78 MB
  ushort* wiWb  = (ushort*)(ws + 16777216);            //  8.39 MB
  ushort* woWb  = (ushort*)(ws + 25165824);            //  8.39 MB
  ushort* inter = (ushort*)(ws + 33554432);            // 67.1  MB
  int*    top1  = (int*)   (ws + 100663296);           // 32 KB
  float*  coeff = (float*) (ws + 100696064);           // 128 KB

  prep_kernel<<<10240, 256, 0, stream>>>(wi_W, wo_W, wiWb, woWb,
                                         x, gate_W, gate_b, lora_A, top1, coeff, xb);
  gemm1_kernel<<<dim3(N_TOK / 128, FDIM / 128), 256, 0, stream>>>(
      xb, wiWb, wi_b, top1, (const float4*)coeff, (const float4*)lora_B, inter);
  gemm2_kernel<<<dim3(N_TOK / 128, DDIM / 128), 256, 0, stream>>>(inter, woWb, wo_b, out);
}